// Round 5
// baseline (143.542 us; speedup 1.0000x reference)
//
#include <hip/hip_runtime.h>
#include <math.h>

// Problem constants (fixed by reference)
#define B_ 8
#define N_ 384
#define D_ 256
#define H_ 1024

typedef __bf16 bh;
typedef __bf16 bh4   __attribute__((ext_vector_type(4)));
typedef __bf16 bf16x8 __attribute__((ext_vector_type(8)));
typedef float  f32x4  __attribute__((ext_vector_type(4)));
typedef _Float16 h2 __attribute__((ext_vector_type(2)));

#if __has_builtin(__builtin_amdgcn_fdot2)
#define FDOT2(a,b,c) __builtin_amdgcn_fdot2((a),(b),(c),false)
#else
#define FDOT2(a,b,c) ((c) + (float)(a).x*(float)(b).x + (float)(a).y*(float)(b).y)
#endif

// async global->LDS, 16B per lane. LDS dest = wave-uniform base + lane*16.
#define GLDS16(gp, lp) __builtin_amdgcn_global_load_lds( \
    (const __attribute__((address_space(1))) unsigned*)(gp), \
    (__attribute__((address_space(3))) unsigned*)(lp), 16, 0, 0)

__device__ inline h2 habs2(h2 x) {
    unsigned u = __builtin_bit_cast(unsigned, x) & 0x7fff7fffu;
    return __builtin_bit_cast(h2, u);
}

// split fp32 -> hi + lo bf16 (3xbf16 trick: a*b ~= ah*bh + ah*bl + al*bh, rel err ~2^-16)
__device__ inline void split2(float v, bh& h, bh& l) {
    h = (bh)v;
    l = (bh)(v - (float)h);
}

// box_num is logically int64; harness may hand int32. box_num >= 1 always, so
// int64-LE layout has all odd words zero -> runtime-detectable.
__device__ inline int load_boxnum(const int* __restrict__ p, int b) {
    bool is64 = ((p[1] | p[3] | p[5] | p[7]) == 0);
    return is64 ? p[2 * b] : p[b];
}

// ---------------- prep: split x / fc1_w / fc2_w into bf16 hi/lo planes ----------------
// block ranges: [0,768) x (786432 f), [768,1024) w1 (262144 f), [1024,1280) w2 (262144 f)
__global__ __launch_bounds__(256) void prep_split(
        const float* __restrict__ x, const float* __restrict__ w1, const float* __restrict__ w2,
        bh* __restrict__ xh, bh* __restrict__ xl,
        bh* __restrict__ w1h, bh* __restrict__ w1l,
        bh* __restrict__ w2h, bh* __restrict__ w2l) {
    const int blk = blockIdx.x;
    const float* src; bh *dh, *dl; int idx;
    if (blk < 768)       { src = x;  dh = xh;  dl = xl;  idx = blk * 256 + threadIdx.x; }
    else if (blk < 1024) { src = w1; dh = w1h; dl = w1l; idx = (blk - 768) * 256 + threadIdx.x; }
    else                 { src = w2; dh = w2h; dl = w2l; idx = (blk - 1024) * 256 + threadIdx.x; }
    float4 v = ((const float4*)src)[idx];
    float f[4] = {v.x, v.y, v.z, v.w};
    bh4 hv, lv;
    #pragma unroll
    for (int i = 0; i < 4; i++) { bh h, l; split2(f[i], h, l); hv[i] = h; lv[i] = l; }
    *(bh4*)&dh[4 * (size_t)idx] = hv;
    *(bh4*)&dl[4 * (size_t)idx] = lv;
}

// ---------------- GEMM1: c1 = relu(x @ fc1_w^T + fc1_b), split hi/lo out ----------------
// 128x128 tile, BK=32, 4 waves (2x2 of 64x64), grid (8,24)=192 blocks.
// LDS planes (8KB each, rows of 64B): 0=Ah 1=Al 2=Bh 3=Bl; 16B k-blocks XOR-swizzled
// by ((row>>1)&3) -> frag reads hit 8 distinct banks (2-way = free).
__global__ __launch_bounds__(256) void gemm1_kernel(
        const bh* __restrict__ xh, const bh* __restrict__ xl,
        const bh* __restrict__ w1h, const bh* __restrict__ w1l,
        const float* __restrict__ bias,
        bh* __restrict__ c1h, bh* __restrict__ c1l) {
    __shared__ __align__(16) bh lds[16384];   // 32 KB
    const int tid = threadIdx.x, lane = tid & 63, w = tid >> 6;
    const int m0 = blockIdx.y * 128, n0 = blockIdx.x * 128;
    // staging constants: wave w owns plane w; lane -> (row-in-chunk, k-block)
    const int lr = lane >> 2, kb = lane & 3;
    const int kbp = kb ^ ((lr >> 1) & 3);
    const bh* psrc; int rowbase;
    if (w == 0)      { psrc = xh;  rowbase = m0; }
    else if (w == 1) { psrc = xl;  rowbase = m0; }
    else if (w == 2) { psrc = w1h; rowbase = n0; }
    else             { psrc = w1l; rowbase = n0; }
    const bh* gsrc = psrc + (size_t)(rowbase + lr) * 256 + kbp * 8;
    bh* lwb = &lds[w * 4096 + lane * 8];
    // fragment constants
    const int l15 = lane & 15, q = lane >> 4;
    const int swq = q ^ ((l15 >> 1) & 3);
    const int wm = (w & 1) * 64, wn = (w >> 1) * 64;

    f32x4 acc[4][4] = {};
    for (int k0 = 0; k0 < 256; k0 += 32) {
        __syncthreads();                         // prior reads done before overwrite
        #pragma unroll
        for (int s = 0; s < 8; s++)
            GLDS16(gsrc + (size_t)s * 4096 + k0, lwb + s * 512);
        __syncthreads();                         // drains vmcnt (loads landed)
        bf16x8 fa[4][2], fb[4][2];
        #pragma unroll
        for (int i = 0; i < 4; i++) {
            int ra = wm + i * 16 + l15;
            int rb = wn + i * 16 + l15;
            fa[i][0] = *(const bf16x8*)&lds[        ra * 32 + swq * 8];
            fa[i][1] = *(const bf16x8*)&lds[ 4096 + ra * 32 + swq * 8];
            fb[i][0] = *(const bf16x8*)&lds[ 8192 + rb * 32 + swq * 8];
            fb[i][1] = *(const bf16x8*)&lds[12288 + rb * 32 + swq * 8];
        }
        #pragma unroll
        for (int mi = 0; mi < 4; mi++)
            #pragma unroll
            for (int ni = 0; ni < 4; ni++) {
                acc[mi][ni] = __builtin_amdgcn_mfma_f32_16x16x32_bf16(fa[mi][0], fb[ni][0], acc[mi][ni], 0, 0, 0);
                acc[mi][ni] = __builtin_amdgcn_mfma_f32_16x16x32_bf16(fa[mi][0], fb[ni][1], acc[mi][ni], 0, 0, 0);
                acc[mi][ni] = __builtin_amdgcn_mfma_f32_16x16x32_bf16(fa[mi][1], fb[ni][0], acc[mi][ni], 0, 0, 0);
            }
    }
    #pragma unroll
    for (int ni = 0; ni < 4; ni++) {
        int col = n0 + wn + ni * 16 + l15;
        float bb = bias[col];
        #pragma unroll
        for (int mi = 0; mi < 4; mi++)
            #pragma unroll
            for (int reg = 0; reg < 4; reg++) {
                int row = m0 + wm + mi * 16 + q * 4 + reg;
                float v = fmaxf(acc[mi][ni][reg] + bb, 0.f);
                bh h, l; split2(v, h, l);
                size_t off = (size_t)row * H_ + col;
                c1h[off] = h; c1l[off] = l;
            }
    }
}

// ---------------- GEMM2: xhat = c1 @ fc2_w^T + fc2_b ----------------
// 64x128 tile, BK=64, 4 waves (each 64m x 32n), grid (2,48)=96 blocks.
// LDS: Ah@0 Al@4096 (8KB ea), Bh@8192 Bl@16384 (16KB ea); rows of 128B,
// 16B k-blocks swizzled by (row&7).
__global__ __launch_bounds__(256) void gemm2_kernel(
        const bh* __restrict__ c1h, const bh* __restrict__ c1l,
        const bh* __restrict__ w2h, const bh* __restrict__ w2l,
        const float* __restrict__ bias,
        float* __restrict__ C) {
    __shared__ __align__(16) bh lds[24576];   // 48 KB
    const int tid = threadIdx.x, lane = tid & 63, w = tid >> 6;
    const int m0 = blockIdx.y * 64, n0 = blockIdx.x * 128;
    // staging: chunks of 1KB = 8 rows x 128B; lane -> (row-in-chunk, k-block)
    const int lr = lane >> 3, kb = lane & 7;
    const int kbp = kb ^ lr;                  // (row&7) == lr since chunk rows are 8-aligned
    const int l15 = lane & 15, q = lane >> 4;
    const int wn = w * 32;

    f32x4 acc[4][2] = {};
    for (int k0 = 0; k0 < 1024; k0 += 64) {
        __syncthreads();
        // 48 chunks: 0..7 Ah, 8..15 Al, 16..31 Bh, 32..47 Bl; wave w takes 12
        #pragma unroll
        for (int j = 0; j < 12; j++) {
            int c = w * 12 + j;
            const bh* g; int ldsbase, s;
            if (c < 8)       { g = c1h; ldsbase = 0;     s = c;      g += (size_t)(m0 + s * 8 + lr) * 1024; }
            else if (c < 16) { g = c1l; ldsbase = 4096;  s = c - 8;  g += (size_t)(m0 + s * 8 + lr) * 1024; }
            else if (c < 32) { g = w2h; ldsbase = 8192;  s = c - 16; g += (size_t)(n0 + s * 8 + lr) * 1024; }
            else             { g = w2l; ldsbase = 16384; s = c - 32; g += (size_t)(n0 + s * 8 + lr) * 1024; }
            GLDS16(g + k0 + kbp * 8, &lds[ldsbase + s * 512 + lane * 8]);
        }
        __syncthreads();
        #pragma unroll
        for (int ks = 0; ks < 2; ks++) {
            const int p = (ks * 4 + q) ^ (l15 & 7);
            bf16x8 fa[4][2], fb[2][2];
            #pragma unroll
            for (int mi = 0; mi < 4; mi++) {
                int ra = mi * 16 + l15;
                fa[mi][0] = *(const bf16x8*)&lds[       ra * 64 + p * 8];
                fa[mi][1] = *(const bf16x8*)&lds[4096 + ra * 64 + p * 8];
            }
            #pragma unroll
            for (int ni = 0; ni < 2; ni++) {
                int rb = wn + ni * 16 + l15;
                fb[ni][0] = *(const bf16x8*)&lds[ 8192 + rb * 64 + p * 8];
                fb[ni][1] = *(const bf16x8*)&lds[16384 + rb * 64 + p * 8];
            }
            #pragma unroll
            for (int mi = 0; mi < 4; mi++)
                #pragma unroll
                for (int ni = 0; ni < 2; ni++) {
                    acc[mi][ni] = __builtin_amdgcn_mfma_f32_16x16x32_bf16(fa[mi][0], fb[ni][0], acc[mi][ni], 0, 0, 0);
                    acc[mi][ni] = __builtin_amdgcn_mfma_f32_16x16x32_bf16(fa[mi][0], fb[ni][1], acc[mi][ni], 0, 0, 0);
                    acc[mi][ni] = __builtin_amdgcn_mfma_f32_16x16x32_bf16(fa[mi][1], fb[ni][0], acc[mi][ni], 0, 0, 0);
                }
        }
    }
    #pragma unroll
    for (int ni = 0; ni < 2; ni++) {
        int col = n0 + wn + ni * 16 + l15;
        float bb = bias[col];
        #pragma unroll
        for (int mi = 0; mi < 4; mi++)
            #pragma unroll
            for (int reg = 0; reg < 4; reg++) {
                int row = m0 + mi * 16 + q * 4 + reg;
                C[(size_t)row * D_ + col] = acc[mi][ni][reg] + bb;
            }
    }
}

// ---------------- pairwise weighted L1 + mask + leaky: symmetric fp16-dot2 ----------------
#define DLP 68
__global__ __launch_bounds__(256) void dist_kernel(const float* __restrict__ xhat,
                                                   const float* __restrict__ w,
                                                   const int* __restrict__ box_num,
                                                   float* __restrict__ dist) {
    __shared__ __align__(16) unsigned XiU[16 * DLP];
    __shared__ __align__(16) unsigned XjU[16 * DLP];
    const int bidx = blockIdx.x;
    const int b = bidx / 21;
    int p = bidx % 21;
    int ti = 0;
    while (p >= 6 - ti) { p -= 6 - ti; ti++; }
    const int tj = ti + p;
    const int i0 = ti * 64, j0 = tj * 64;

    const int tid = threadIdx.x;
    const int tx = tid & 15, ty = tid >> 4;
    const int lane = tid & 63;
    const int r = tid >> 2, kq = (tid & 3) * 8;
    const int kq2 = (tid & 3) * 4;

    float sumw = w[lane] + w[lane + 64] + w[lane + 128] + w[lane + 192];
    #pragma unroll
    for (int off = 32; off > 0; off >>= 1) sumw += __shfl_xor(sumw, off);

    const float* xb = xhat + (size_t)b * N_ * D_;
    float acc[4][4] = {};

    for (int k0 = 0; k0 < D_; k0 += 32) {
        h2 wk2[16];
        #pragma unroll
        for (int c = 0; c < 16; c++) {
            float2 wp = *(const float2*)&w[k0 + 2 * c];
            wk2[c] = (h2){(_Float16)wp.x, (_Float16)wp.y};
        }
        const float* ip = xb + (size_t)(i0 + r) * D_ + k0 + kq;
        const float* jp = xb + (size_t)(j0 + r) * D_ + k0 + kq;
        float4 i0v = *(const float4*)ip, i1v = *(const float4*)(ip + 4);
        float4 j0v = *(const float4*)jp, j1v = *(const float4*)(jp + 4);
        float fi[8] = {i0v.x, i0v.y, i0v.z, i0v.w, i1v.x, i1v.y, i1v.z, i1v.w};
        float fj[8] = {j0v.x, j0v.y, j0v.z, j0v.w, j1v.x, j1v.y, j1v.z, j1v.w};
        __syncthreads();
        #pragma unroll
        for (int c = 0; c < 4; c++) {
            h2 hi = (h2){(_Float16)fi[2 * c], (_Float16)fi[2 * c + 1]};
            h2 hj = (h2){(_Float16)fj[2 * c], (_Float16)fj[2 * c + 1]};
            XiU[(kq2 + c) * DLP + r] = __builtin_bit_cast(unsigned, hi);
            XjU[(kq2 + c) * DLP + r] = __builtin_bit_cast(unsigned, hj);
        }
        __syncthreads();
        #pragma unroll
        for (int k2 = 0; k2 < 16; k2++) {
            uint4 ar = *(const uint4*)&XiU[k2 * DLP + ty * 4];
            uint4 br = *(const uint4*)&XjU[k2 * DLP + tx * 4];
            h2 ai[4] = {__builtin_bit_cast(h2, ar.x), __builtin_bit_cast(h2, ar.y),
                        __builtin_bit_cast(h2, ar.z), __builtin_bit_cast(h2, ar.w)};
            h2 bj[4] = {__builtin_bit_cast(h2, br.x), __builtin_bit_cast(h2, br.y),
                        __builtin_bit_cast(h2, br.z), __builtin_bit_cast(h2, br.w)};
            h2 wv = wk2[k2];
            #pragma unroll
            for (int ii = 0; ii < 4; ii++)
                #pragma unroll
                for (int jj = 0; jj < 4; jj++) {
                    h2 d = habs2(ai[ii] - bj[jj]);
                    acc[ii][jj] = FDOT2(d, wv, acc[ii][jj]);
                }
        }
    }

    const int bn = load_boxnum(box_num, b);
    float m[4][4];
    #pragma unroll
    for (int ii = 0; ii < 4; ii++) {
        int i = i0 + ty * 4 + ii;
        bool vi = i < bn;
        #pragma unroll
        for (int jj = 0; jj < 4; jj++) {
            int j = j0 + tx * 4 + jj;
            float v = acc[ii][jj];
            if (!(vi && (j < bn))) v -= sumw;
            m[ii][jj] = v > 0.f ? v : 0.01f * v;
        }
    }
    #pragma unroll
    for (int ii = 0; ii < 4; ii++) {
        int i = i0 + ty * 4 + ii;
        float4 o = {m[ii][0], m[ii][1], m[ii][2], m[ii][3]};
        *(float4*)&dist[((size_t)b * N_ + i) * N_ + j0 + tx * 4] = o;
    }
    #pragma unroll
    for (int jj = 0; jj < 4; jj++) {
        int j = j0 + tx * 4 + jj;
        float4 o = {m[0][jj], m[1][jj], m[2][jj], m[3][jj]};
        *(float4*)&dist[((size_t)b * N_ + j) * N_ + i0 + ty * 4] = o;
    }
}

// ---------------- row softmax: 4 waves per block, one row per wave ----------------
__global__ __launch_bounds__(256) void softmax_kernel(float* __restrict__ sa,
                                                      const float* __restrict__ adj) {
    const int row = blockIdx.x * 4 + (threadIdx.x >> 6);
    const int t = threadIdx.x & 63;
    float* prow = sa + (size_t)row * N_;
    const float* arow = adj + (size_t)row * N_;
    float v[6];
    float m = -1e30f;
    #pragma unroll
    for (int qq = 0; qq < 6; qq++) { v[qq] = prow[t + qq * 64]; m = fmaxf(m, v[qq]); }
    #pragma unroll
    for (int off = 32; off > 0; off >>= 1) m = fmaxf(m, __shfl_xor(m, off));
    float e[6];
    float s = 0.f;
    #pragma unroll
    for (int qq = 0; qq < 6; qq++) { e[qq] = arow[t + qq * 64] * expf(v[qq] - m); s += e[qq]; }
    #pragma unroll
    for (int off = 32; off > 0; off >>= 1) s += __shfl_xor(s, off);
    float inv = 1.0f / s;
    #pragma unroll
    for (int qq = 0; qq < 6; qq++) prow[t + qq * 64] = e[qq] * inv + 1e-10f;
}

extern "C" void kernel_launch(void* const* d_in, const int* in_sizes, int n_in,
                              void* d_out, int out_size, void* d_ws, size_t ws_size,
                              hipStream_t stream) {
    const float* x       = (const float*)d_in[0];
    const float* adj     = (const float*)d_in[1];
    const int*   box_num = (const int*)d_in[2];
    const float* fc1_w   = (const float*)d_in[3];
    const float* fc1_b   = (const float*)d_in[4];
    const float* fc2_w   = (const float*)d_in[5];
    const float* fc2_b   = (const float*)d_in[6];
    const float* learn_w = (const float*)d_in[7];

    float* soft_adj = (float*)d_out;
    float* xhat     = (float*)d_out + (size_t)B_ * N_ * N_;

    // ws layout (bh units): xh, xl (786432 ea) | w1h, w1l (262144 ea) |
    // w2h, w2l (262144 ea) | c1h, c1l (3145728 ea)  -> 17.8 MB total
    bh* xh  = (bh*)d_ws;
    bh* xl  = xh  + 786432;
    bh* w1h = xl  + 786432;
    bh* w1l = w1h + 262144;
    bh* w2h = w1l + 262144;
    bh* w2l = w2h + 262144;
    bh* c1h = w2l + 262144;
    bh* c1l = c1h + 3145728;

    prep_split<<<1280, 256, 0, stream>>>(x, fc1_w, fc2_w, xh, xl, w1h, w1l, w2h, w2l);

    dim3 g1(H_ / 128, (B_ * N_) / 128);   // (8,24)
    gemm1_kernel<<<g1, 256, 0, stream>>>(xh, xl, w1h, w1l, fc1_b, c1h, c1l);

    dim3 g2(D_ / 128, (B_ * N_) / 64);    // (2,48)
    gemm2_kernel<<<g2, 256, 0, stream>>>(c1h, c1l, w2h, w2l, fc2_b, xhat);

    dist_kernel<<<B_ * 21, 256, 0, stream>>>(xhat, learn_w, box_num, soft_adj);

    softmax_kernel<<<(B_ * N_) / 4, 256, 0, stream>>>(soft_adj, adj);
}